// Round 1
// baseline (169.746 us; speedup 1.0000x reference)
//
#include <hip/hip_runtime.h>
#include <hip/hip_bf16.h>

// all I/O is float32 (reference is pure jnp.float32)

typedef __attribute__((ext_vector_type(8))) short bf16x8;
typedef __attribute__((ext_vector_type(4))) float f32x4;

// ---- ws layout (f32 element offsets) ----
#define O_WPK   0          // Wpack [tap9][cb16][co64][cin32] bf16 (big convs)
#define O_W51P  147456     // [tap9][co32][ci32] bf16
#define O_W52P  152064
#define O_BNA   156672     // [conv{5a,5c,51,52}][{A,B}][32]
#define O_W8    156928     // w8[2][32], b8 at +64
#define O_PQW   157000     // [4][32], bias at +128
#define O_PKW   157132
#define O_PVW   157264     // [32][32], bias at +1024
#define O_GAM   158320     // p_gamma, c_gamma
#define O_Q     158400     // [b4][cr4][4096] f32
#define O_K     223936     // [b4][cr4][4096] f32
#define O_ENE   453312     // [4][32][32]
#define O_ATT   457408
#define O_F1T   985792     // [b][4096][32] f32 NHWC
#define O_F2T   1510080    // [b][4096][32] f32 NHWC
#define O_V     2034368    // [b][32][4096] bf16
#define O_SAT   2558656    // [b][66][66][32] bf16 padded
#define O_SCT   2837440
// conv-phase overlays (Xt dead before F1T/SAT written):
#define O_XT    461504     // Xt[b4][cb16][66][66][32] bf16 (ends 4922048)
#define O_CP    4922048    // conv partials f32 [ks2][b4][4096pix][64co] (ends 7019200)

__device__ __forceinline__ unsigned short f2b(float f){
  __hip_bfloat16 h = __float2bfloat16(f);
  return *(unsigned short*)&h;
}

// ---------------- prep: pack big conv weights to bf16 [tap][cb][co64][cin32] ----------------
__global__ __launch_bounds__(256) void k_prep_wpack(const float* w5a, const float* w5c, float* ws){
  int id = blockIdx.x*256 + threadIdx.x;   // 294912
  int tap = id >> 15;
  int r = id & 32767;
  int cb = r >> 11;
  int r2 = r & 2047;
  int co = r2 >> 5, ci = r2 & 31;
  int cin = cb*32 + ci;
  float v = (co < 32) ? w5a[co*4608 + cin*9 + tap] : w5c[(co-32)*4608 + cin*9 + tap];
  ((unsigned short*)ws)[id] = f2b(v);
}

__global__ __launch_bounds__(256) void k_prep_misc(
  const float* w51, const float* w52,
  const float* s0,const float* b0,const float* m0,const float* v0,
  const float* s1,const float* b1,const float* m1,const float* v1,
  const float* s2,const float* b2,const float* m2,const float* v2,
  const float* s3,const float* b3,const float* m3,const float* v3,
  const float* w8,const float* b8,
  const float* pqw,const float* pqb,const float* pkw,const float* pkb,
  const float* pvw,const float* pvb,const float* pg,const float* cg,
  float* ws)
{
  int id = blockIdx.x*256 + threadIdx.x;
  if (id >= 20076) return;
  if (id < 9216){ int tap=id>>10, co=(id>>5)&31, ci=id&31;
    ((unsigned short*)(ws + O_W51P))[id] = f2b(w51[co*288 + ci*9 + tap]); return; }
  id -= 9216;
  if (id < 9216){ int tap=id>>10, co=(id>>5)&31, ci=id&31;
    ((unsigned short*)(ws + O_W52P))[id] = f2b(w52[co*288 + ci*9 + tap]); return; }
  id -= 9216;
  if (id < 256){
    int conv = id>>6, ab = (id>>5)&1, c = id&31;
    const float *S,*Bb,*M,*V;
    if (conv==0){S=s0;Bb=b0;M=m0;V=v0;} else if (conv==1){S=s1;Bb=b1;M=m1;V=v1;}
    else if (conv==2){S=s2;Bb=b2;M=m2;V=v2;} else {S=s3;Bb=b3;M=m3;V=v3;}
    float A = S[c] * rsqrtf(V[c] + 1e-5f);
    ws[O_BNA + conv*64 + ab*32 + c] = ab ? (Bb[c] - M[c]*A) : A;
    return; }
  id -= 256;
  if (id < 64){ ws[O_W8+id] = w8[id]; return; } id -= 64;
  if (id < 2){ ws[O_W8+64+id] = b8[id]; return; } id -= 2;
  if (id < 128){ ws[O_PQW+id] = pqw[id]; return; } id -= 128;
  if (id < 4){ ws[O_PQW+128+id] = pqb[id]; return; } id -= 4;
  if (id < 128){ ws[O_PKW+id] = pkw[id]; return; } id -= 128;
  if (id < 4){ ws[O_PKW+128+id] = pkb[id]; return; } id -= 4;
  if (id < 1024){ ws[O_PVW+id] = pvw[id]; return; } id -= 1024;
  if (id < 32){ ws[O_PVW+1024+id] = pvb[id]; return; } id -= 32;
  ws[O_GAM+id] = id ? cg[0] : pg[0];
}

// ---------------- zero Xt borders only (ring of 260 px per (b,cb)) ----------------
__global__ __launch_bounds__(256) void k_zero_xtb(float* __restrict__ ws){
  int i = blockIdx.x*256 + threadIdx.x;   // 66560 uint4
  if (i >= 66560) return;
  int part = i & 3; int j = i >> 2;       // 16640
  int rp = j % 260; int bc = j / 260;     // bc = b*16+cb
  int py, px;
  if (rp < 66){ py = 0; px = rp; }
  else if (rp < 132){ py = 65; px = rp - 66; }
  else if (rp < 196){ py = rp - 131; px = 0; }
  else { py = rp - 195; px = 65; }
  size_t off = (((size_t)bc*66 + py)*66 + px)*32 + part*8;
  *(uint4*)((unsigned short*)(ws + O_XT) + off) = make_uint4(0,0,0,0);
}

// ---------------- zero SA_t / SC_t borders ----------------
__global__ __launch_bounds__(256) void k_zero_sascb(float* __restrict__ ws){
  int i = blockIdx.x*256 + threadIdx.x;   // 8320 uint4
  if (i >= 8320) return;
  int part = i & 3; int j = i >> 2;       // 2080
  int arr = j / 1040; int rem = j - arr*1040;
  int b = rem / 260; int rp = rem % 260;
  int py, px;
  if (rp < 66){ py = 0; px = rp; }
  else if (rp < 132){ py = 65; px = rp - 66; }
  else if (rp < 196){ py = rp - 131; px = 0; }
  else { py = rp - 195; px = 65; }
  size_t off = (((size_t)(b*66) + py)*66 + px)*32 + part*8;
  unsigned short* base = (unsigned short*)(ws + O_SAT + arr*278784);
  *(uint4*)(base + off) = make_uint4(0,0,0,0);
}

// ---------------- NHWC+pad bf16 transform: Xt[b][cb16][66][66][32] ----------------
__global__ __launch_bounds__(256) void k_nhwc(const float* __restrict__ x, float* __restrict__ ws){
  int y = blockIdx.x, ct = blockIdx.y, b = blockIdx.z;  // (64, 8, 4)
  __shared__ unsigned short t16[64][65];
  int tid = threadIdx.x;
  int r0 = tid >> 4, c0 = (tid & 15) * 4;
  const float* xb = x + ((size_t)(b*512 + ct*64))*4096 + y*64;
  #pragma unroll
  for (int i = 0; i < 4; ++i){
    int row = r0 + i*16;
    float4 v = *(const float4*)(xb + (size_t)row*4096 + c0);
    t16[row][c0+0] = f2b(v.x);
    t16[row][c0+1] = f2b(v.y);
    t16[row][c0+2] = f2b(v.z);
    t16[row][c0+3] = f2b(v.w);
  }
  __syncthreads();
  int pixl = tid >> 2, q = tid & 3;
  unsigned short vs[16];
  #pragma unroll
  for (int j = 0; j < 16; ++j) vs[j] = t16[q*16 + j][pixl];
  unsigned u[8];
  #pragma unroll
  for (int j = 0; j < 8; ++j) u[j] = (unsigned)vs[2*j] | ((unsigned)vs[2*j+1] << 16);
  unsigned short* xt = (unsigned short*)(ws + O_XT);
  int cbl = ct*2 + (q>>1);
  size_t off = (((size_t)(b*16 + cbl)*66 + (y+1))*66 + (pixl+1))*32 + (q&1)*16;
  *(uint4*)(xt + off)     = make_uint4(u[0],u[1],u[2],u[3]);
  *(uint4*)(xt + off + 8) = make_uint4(u[4],u[5],u[6],u[7]);
}

// ---------------- big convs as implicit GEMM via MFMA (row-slab staging) ----------------
__global__ __launch_bounds__(256) void k_conv_mfma(float* __restrict__ ws){
  int mb = blockIdx.x;          // b = mb>>6, y = mb&63
  int ks = blockIdx.y;          // cin half
  int b = mb >> 6, y = mb & 63;
  __shared__ unsigned short Bs[198*40];   // [dy*66+px][k32 pad40]
  int tid = threadIdx.x;
  int w = tid >> 6, l = tid & 63;
  f32x4 zero = {0.f,0.f,0.f,0.f};
  f32x4 acc[4] = {zero, zero, zero, zero};
  const unsigned short* wp = (const unsigned short*)ws;
  const unsigned short* xt = (const unsigned short*)(ws + O_XT);
  int arow = w*16 + (l & 15);
  int kq = (l >> 4)*8;
  for (int cb8 = 0; cb8 < 8; ++cb8){
    int cb = ks*8 + cb8;
    const unsigned short* slab = xt + ((size_t)((b*16 + cb)*66 + y))*66*32;
    __syncthreads();
    for (int i = tid; i < 792; i += 256)
      *(uint4*)&Bs[(i>>2)*40 + (i&3)*8] = *(const uint4*)(slab + i*8);
    __syncthreads();
    #pragma unroll
    for (int tap = 0; tap < 9; ++tap){
      int dy = tap/3, dx = tap - dy*3;
      bf16x8 af = *(const bf16x8*)(wp + (size_t)(tap*16 + cb)*2048 + arow*32 + kq);
      #pragma unroll
      for (int pt = 0; pt < 4; ++pt){
        int pix = pt*16 + (l&15) + dx;
        bf16x8 bv = *(const bf16x8*)&Bs[(dy*66 + pix)*40 + kq];
        acc[pt] = __builtin_amdgcn_mfma_f32_16x16x32_bf16(af, bv, acc[pt], 0, 0, 0);
      }
    }
  }
  float* cp = ws + O_CP + ((size_t)(ks*4 + b))*262144;
  int co0 = w*16 + (l>>4)*4;
  #pragma unroll
  for (int pt = 0; pt < 4; ++pt){
    int pix = y*64 + pt*16 + (l & 15);
    *(f32x4*)&cp[(size_t)pix*64 + co0] = acc[pt];
  }
}

// ---------------- reduce partials + BN + ReLU -> F1T, F2T (coalesced) ----------------
__global__ __launch_bounds__(256) void k_reduce_feat(float* __restrict__ ws){
  int id = blockIdx.x*256 + threadIdx.x;     // 1048576 = (b*4096+pix)*64 + co
  float s = ws[O_CP + id] + ws[O_CP + 1048576 + id];
  int co = id & 63; int rest = id >> 6;      // b*4096+pix
  int conv = co >> 5, c = co & 31;
  float A = ws[O_BNA + conv*64 + c], Bb = ws[O_BNA + conv*64 + 32 + c];
  float val = fmaxf(A*s + Bb, 0.f);
  if (conv == 0) ws[O_F1T + (size_t)rest*32 + c] = val;
  else           ws[O_F2T + (size_t)rest*32 + c] = val;
}

// ---------------- q,k,v 1x1 convs (Q,K f32; V bf16) ----------------
// 256 blocks; thread = (part, b, n): part-th cr of q/k + 8 V channels
__global__ __launch_bounds__(256) void k_qkv(float* __restrict__ ws){
  int id = blockIdx.x*256 + threadIdx.x;  // 65536
  int part = id >> 14;                    // 0..3 (uniform per block)
  int nid = id & 16383;                   // b*4096+n
  int b = nid >> 12, n = nid & 4095;
  __shared__ float wq[32], wk[32], wv[8][32];
  int tid = threadIdx.x;
  if (tid < 32){ wq[tid] = ws[O_PQW + part*32 + tid]; wk[tid] = ws[O_PKW + part*32 + tid]; }
  wv[tid>>5][tid&31] = ws[O_PVW + (part*8 + (tid>>5))*32 + (tid&31)];
  __syncthreads();
  const float* fp = ws + O_F1T + (size_t)nid*32;
  float fv[32];
  #pragma unroll
  for (int j=0;j<8;j++){
    float4 v = *(const float4*)(fp + j*4);
    fv[j*4]=v.x; fv[j*4+1]=v.y; fv[j*4+2]=v.z; fv[j*4+3]=v.w;
  }
  float q = ws[O_PQW+128+part], k = ws[O_PKW+128+part];
  #pragma unroll
  for (int c=0;c<32;c++){ q += wq[c]*fv[c]; k += wk[c]*fv[c]; }
  ws[O_Q + (((b<<2)+part)<<12) + n] = q;
  ws[O_K + (((b<<2)+part)<<12) + n] = k;
  unsigned short* vbp = (unsigned short*)(ws + O_V);
  #pragma unroll
  for (int j2=0;j2<8;j2++){
    int c2 = part*8 + j2;
    float v = ws[O_PVW+1024+c2];
    #pragma unroll
    for (int c=0;c<32;c++) v += wv[j2][c]*fv[c];
    vbp[(((b<<5)+c2)<<12) + n] = f2b(v);
  }
}

// ---------------- PAM flash: QK^T (f32 FMA, direct L2 loads) + fixed-shift softmax
//                  + MFMA P@V + MFMA ones-trick denominator -> SA_t ----------------
// No LDS staging: V A-fragment (c=l&15, m=mo..mo+7) and K broadcast reads map onto
// full 64B L2 lines directly; the old LDS bounce was pure overhead (bank conflicts).
__global__ __launch_bounds__(256, 4) void k_pam_flash(float* __restrict__ ws){
  int nt = blockIdx.x;   // 0..255 n-tile of 16
  int b  = blockIdx.y;
  __shared__ float Ss[4][16];
  __shared__ float Os[4][16][36];
  int tid = threadIdx.x;
  int w = tid >> 6, l = tid & 63;
  int nn = l & 15, g = l >> 4;
  int n = (nt<<4) + nn;
  const float LOG2E = 1.44269504f;
  const float BIAS  = -28.8539008f;   // -20 * log2(e); softmax shift-invariant, energies O(+-35)
  float q[4];
  #pragma unroll
  for (int cr=0;cr<4;++cr) q[cr] = ws[O_Q + (((b<<2)+cr)<<12) + n] * LOG2E;
  int mo = g*8;
  int mbase = w*1024 + mo;            // wave w owns m in [w*1024, w*1024+1024)
  const float* kp[4];
  #pragma unroll
  for (int cr=0;cr<4;++cr) kp[cr] = ws + O_K + (((b<<2)+cr)<<12) + mbase;
  const unsigned short* vbp = (const unsigned short*)(ws + O_V);
  const unsigned short* vp0 = vbp + (((b<<5) + nn)<<12) + mbase;
  const unsigned short* vp1 = vbp + (((b<<5) + 16 + nn)<<12) + mbase;
  f32x4 zero = {0.f,0.f,0.f,0.f};
  f32x4 acc0 = zero, acc1 = zero, accS = zero;
  union { bf16x8 v; unsigned short u[8]; } ones;
  #pragma unroll
  for (int j=0;j<8;++j) ones.u[j] = 0x3F80;   // bf16 1.0
  for (int ch = 0; ch < 32; ++ch){
    int m0 = ch*32;
    f32x4 ka[4], kb[4];
    #pragma unroll
    for (int cr=0;cr<4;++cr){
      ka[cr] = *(const f32x4*)(kp[cr] + m0);
      kb[cr] = *(const f32x4*)(kp[cr] + m0 + 4);
    }
    bf16x8 a0 = *(const bf16x8*)(vp0 + m0);
    bf16x8 a1 = *(const bf16x8*)(vp1 + m0);
    union { bf16x8 v; unsigned short u[8]; } pb;
    #pragma unroll
    for (int j=0;j<4;++j){
      float e0 = fmaf(q[0], ka[0][j], BIAS);
      float e1 = fmaf(q[0], kb[0][j], BIAS);
      #pragma unroll
      for (int cr=1;cr<4;++cr){
        e0 = fmaf(q[cr], ka[cr][j], e0);
        e1 = fmaf(q[cr], kb[cr][j], e1);
      }
      pb.u[j]   = f2b(__builtin_amdgcn_exp2f(e0));
      pb.u[j+4] = f2b(__builtin_amdgcn_exp2f(e1));
    }
    acc0 = __builtin_amdgcn_mfma_f32_16x16x32_bf16(a0, pb.v, acc0, 0, 0, 0);
    acc1 = __builtin_amdgcn_mfma_f32_16x16x32_bf16(a1, pb.v, acc1, 0, 0, 0);
    accS = __builtin_amdgcn_mfma_f32_16x16x32_bf16(ones.v, pb.v, accS, 0, 0, 0);
  }
  // accS rows are all identical = sum_m P[n][m] over this wave's m-range
  if (l < 16) Ss[w][l] = accS[0];
  #pragma unroll
  for (int r=0;r<4;r++){
    Os[w][nn][g*4 + r]      = acc0[r];
    Os[w][nn][16 + g*4 + r] = acc1[r];
  }
  __syncthreads();
  float gamma = ws[O_GAM];
  unsigned short* sat = (unsigned short*)(ws + O_SAT);
  for (int i = tid; i < 512; i += 256){
    int nn2 = i >> 5, c = i & 31;
    float S = Ss[0][nn2] + Ss[1][nn2] + Ss[2][nn2] + Ss[3][nn2];
    float o = (Os[0][nn2][c] + Os[1][nn2][c] + Os[2][nn2][c] + Os[3][nn2][c]) / S;
    int pix = (nt<<4) + nn2;
    float sa = gamma*o + ws[O_F1T + ((((size_t)b<<12) + pix)<<5) + c];
    int y = pix >> 6, xx = pix & 63;
    sat[(((size_t)((b*66 + y+1)*66 + xx+1))<<5) + c] = f2b(sa);
  }
}

// ---------------- CAM energy ----------------
__global__ __launch_bounds__(256) void k_cam_energy(float* __restrict__ ws){
  int c = blockIdx.x & 31, b = blockIdx.x >> 5;
  int tid = threadIdx.x;
  int w = tid >> 6, lane = tid & 63;
  const float* f = ws + O_F2T + ((size_t)b<<17);   // [n][32]
  float acc[32];
  #pragma unroll
  for (int d=0;d<32;d++) acc[d]=0.f;
  for (int n=tid; n<4096; n+=256){
    const float* fp = f + (size_t)n*32;
    float fv[32];
    #pragma unroll
    for (int j=0;j<8;j++){
      float4 v = *(const float4*)(fp + j*4);
      fv[j*4]=v.x; fv[j*4+1]=v.y; fv[j*4+2]=v.z; fv[j*4+3]=v.w;
    }
    float fc = fv[c];
    #pragma unroll
    for (int d=0;d<32;d++) acc[d] += fc * fv[d];
  }
  __shared__ float part[4][32];
  #pragma unroll
  for (int d=0;d<32;d++){
    float v = acc[d];
    for (int off=32; off; off>>=1) v += __shfl_down(v, off);
    if (lane==0) part[w][d] = v;
    __syncthreads();
    if (tid == 0) ws[O_ENE + (b<<10) + (c<<5) + d] = part[0][d]+part[1][d]+part[2][d]+part[3][d];
    __syncthreads();
  }
}

// ---------------- CAM att (in-block) + out -> SC_t ----------------
// 128 blocks; thread = (half, 128 n): 16 output channels each
__global__ __launch_bounds__(256) void k_cam_out(float* __restrict__ ws){
  int blk = blockIdx.x;            // 128
  int b = blk >> 5;
  int chunk = blk & 31;
  int tid = threadIdx.x;
  int half = tid >> 7;             // 0/1
  int nl = tid & 127;
  int n = (chunk << 7) + nl;
  __shared__ float att[32][33];
  if (tid < 32){
    int c = tid;
    const float* e = ws + O_ENE + (b<<10) + (c<<5);
    float M = -1e30f, mn = 1e30f;
    #pragma unroll
    for (int d=0;d<32;d++){ M = fmaxf(M, e[d]); mn = fminf(mn, e[d]); }
    float mx2 = M - mn;
    float s = 0.f, ex[32];
    #pragma unroll
    for (int d=0;d<32;d++){ ex[d] = __expf((M - e[d]) - mx2); s += ex[d]; }
    float inv = 1.f/s;
    #pragma unroll
    for (int d=0;d<32;d++) att[c][d] = ex[d]*inv;
  }
  __syncthreads();
  const float* fp = ws + O_F2T + (((size_t)b<<12) + n)*32;
  float fv[32];
  #pragma unroll
  for (int j=0;j<8;j++){
    float4 v = *(const float4*)(fp + j*4);
    fv[j*4]=v.x; fv[j*4+1]=v.y; fv[j*4+2]=v.z; fv[j*4+3]=v.w;
  }
  float g = ws[O_GAM+1];
  int c0 = half*16;
  unsigned u[8];
  #pragma unroll
  for (int cp=0; cp<8; ++cp){
    int ca = c0 + 2*cp, cb = ca + 1;
    float o0 = 0.f, o1 = 0.f;
    #pragma unroll
    for (int d=0;d<32;d++){ o0 += att[ca][d]*fv[d]; o1 += att[cb][d]*fv[d]; }
    float r0 = g*o0 + fv[ca], r1 = g*o1 + fv[cb];
    u[cp] = (unsigned)f2b(r0) | ((unsigned)f2b(r1) << 16);
  }
  int y = n >> 6, xcol = n & 63;
  unsigned short* sct = (unsigned short*)(ws + O_SCT);
  size_t base = ((size_t)((b*66 + y+1)*66 + xcol+1))*32 + c0;
  *(uint4*)(sct + base)     = make_uint4(u[0],u[1],u[2],u[3]);
  *(uint4*)(sct + base + 8) = make_uint4(u[4],u[5],u[6],u[7]);
}

// ---------------- fused conv51+conv52 (MFMA) + BN/ReLU + sum + 1x1 conv8 + ReLU ----------------
__global__ __launch_bounds__(256) void k_final_mfma(float* __restrict__ ws, float* __restrict__ out){
  int y = blockIdx.x, b = blockIdx.y;          // (64, 4)
  __shared__ unsigned short Bs[2*3*66*40];     // [conv][dy][pix66][k32 pad40]
  __shared__ float ep[2][2][2][16];            // [wavepair][pt][o][pix16]
  int tid = threadIdx.x;
  int w = tid >> 6, l = tid & 63;
  int g = l >> 4, col = l & 15;
  const unsigned short* sat = (const unsigned short*)(ws + O_SAT);
  const unsigned short* sct = (const unsigned short*)(ws + O_SCT);
  for (int i = tid; i < 1584; i += 256){
    int row = i >> 2, part = i & 3;
    int conv = row / 198; int rr = row - conv*198;
    int dy = rr / 66; int pix = rr - dy*66;
    const unsigned short* src = (conv ? sct : sat) + ((size_t)((b*66 + y + dy)*66 + pix))*32 + part*8;
    *(uint4*)&Bs[(size_t)row*40 + part*8] = *(const uint4*)src;
  }
  __syncthreads();
  int cohalf = w & 1, ptbase = (w >> 1) * 2;
  const unsigned short* wp[2] = { (const unsigned short*)(ws + O_W51P), (const unsigned short*)(ws + O_W52P) };
  f32x4 zero = {0.f,0.f,0.f,0.f};
  f32x4 acc[2][2] = {{zero,zero},{zero,zero}};
  for (int dy = 0; dy < 3; ++dy){
    for (int dx = 0; dx < 3; ++dx){
      int tap = dy*3 + dx;
      #pragma unroll
      for (int conv = 0; conv < 2; ++conv){
        bf16x8 af = *(const bf16x8*)(wp[conv] + tap*1024 + (cohalf*16 + col)*32 + g*8);
        #pragma unroll
        for (int pt = 0; pt < 2; ++pt){
          int pix = (ptbase + pt)*16 + col + dx;
          bf16x8 bv = *(const bf16x8*)&Bs[(size_t)((conv*3 + dy)*66 + pix)*40 + g*8];
          acc[conv][pt] = __builtin_amdgcn_mfma_f32_16x16x32_bf16(af, bv, acc[conv][pt], 0, 0, 0);
        }
      }
    }
  }
  float p0[2], p1[2];
  #pragma unroll
  for (int pt = 0; pt < 2; ++pt){
    float s0 = 0.f, s1 = 0.f;
    #pragma unroll
    for (int r = 0; r < 4; ++r){
      int co = cohalf*16 + g*4 + r;
      float A1 = ws[O_BNA + 2*64 + co], B1 = ws[O_BNA + 2*64 + 32 + co];
      float A2 = ws[O_BNA + 3*64 + co], B2 = ws[O_BNA + 3*64 + 32 + co];
      float fs = fmaxf(A1*acc[0][pt][r] + B1, 0.f) + fmaxf(A2*acc[1][pt][r] + B2, 0.f);
      s0 += ws[O_W8 + co]*fs;
      s1 += ws[O_W8 + 32 + co]*fs;
    }
    s0 += __shfl_xor(s0, 16); s0 += __shfl_xor(s0, 32);
    s1 += __shfl_xor(s1, 16); s1 += __shfl_xor(s1, 32);
    p0[pt] = s0; p1[pt] = s1;
  }
  if (cohalf == 0 && l < 16){
    #pragma unroll
    for (int pt = 0; pt < 2; ++pt){ ep[w>>1][pt][0][l] = p0[pt]; ep[w>>1][pt][1][l] = p1[pt]; }
  }
  __syncthreads();
  if (cohalf == 1 && l < 16){
    float b80 = ws[O_W8 + 64], b81 = ws[O_W8 + 65];
    #pragma unroll
    for (int pt = 0; pt < 2; ++pt){
      int pix = y*64 + (w>>1)*32 + pt*16 + l;
      float o0 = p0[pt] + ep[w>>1][pt][0][l] + b80;
      float o1 = p1[pt] + ep[w>>1][pt][1][l] + b81;
      out[((b*2+0)<<12) + pix] = fmaxf(o0, 0.f);
      out[((b*2+1)<<12) + pix] = fmaxf(o1, 0.f);
    }
  }
}

extern "C" void kernel_launch(void* const* d_in, const int* in_sizes, int n_in,
                              void* d_out, int out_size, void* d_ws, size_t ws_size,
                              hipStream_t stream) {
  const float* x    = (const float*)d_in[0];
  const float* w5a  = (const float*)d_in[1];
  const float* w5c  = (const float*)d_in[18];
  const float* w51  = (const float*)d_in[13];
  const float* w52  = (const float*)d_in[24];
  float* ws = (float*)d_ws;
  float* out = (float*)d_out;

  k_prep_wpack<<<1152, 256, 0, stream>>>(w5a, w5c, ws);
  k_prep_misc<<<79, 256, 0, stream>>>(
      w51, w52,
      (const float*)d_in[2],(const float*)d_in[3],(const float*)d_in[4],(const float*)d_in[5],
      (const float*)d_in[19],(const float*)d_in[20],(const float*)d_in[21],(const float*)d_in[22],
      (const float*)d_in[14],(const float*)d_in[15],(const float*)d_in[16],(const float*)d_in[17],
      (const float*)d_in[25],(const float*)d_in[26],(const float*)d_in[27],(const float*)d_in[28],
      (const float*)d_in[29],(const float*)d_in[30],
      (const float*)d_in[6],(const float*)d_in[7],(const float*)d_in[8],(const float*)d_in[9],
      (const float*)d_in[10],(const float*)d_in[11],(const float*)d_in[12],(const float*)d_in[23],
      ws);
  k_zero_xtb<<<260, 256, 0, stream>>>(ws);
  k_nhwc<<<dim3(64,8,4), 256, 0, stream>>>(x, ws);
  k_conv_mfma<<<dim3(256,2), 256, 0, stream>>>(ws);
  k_reduce_feat<<<4096, 256, 0, stream>>>(ws);
  k_zero_sascb<<<33, 256, 0, stream>>>(ws);
  k_qkv<<<256, 256, 0, stream>>>(ws);
  k_pam_flash<<<dim3(256,4), 256, 0, stream>>>(ws);
  k_cam_energy<<<128, 256, 0, stream>>>(ws);
  k_cam_out<<<128, 256, 0, stream>>>(ws);
  k_final_mfma<<<dim3(64,4), 256, 0, stream>>>(ws, out);
}